// Round 1
// baseline (5669.841 us; speedup 1.0000x reference)
//
#include <hip/hip_runtime.h>

// PatternConv3d: out[b,co,t,y,x] = bias[y%8,x%8,co]
//   + sum_{ci,kd,kh,kw} X[b,ci,t+kd-1, y+kh-7, x+kw-7] * W[y%8,x%8,co,ci,kd,kh,kw]
// X: (2,64,16,112,112) f32; W: (8,8,64,64,3,3,3) f32; bias: (8,8,64) f32.
//
// Block = (h, b, t, co_tile(16 of 64), ho_half(7 of 14)). 256 threads:
//   xl = tid&127 (x position, valid < 112), cg = tid>>7 (co half of tile).
//   Each thread: 8 co x 7 ho accumulators. w-pattern = x%8 varies per lane.
// Per ci: stage X rows (3kd x 3kh x 7ho x 114 cols, zero-clipped) and
// W (8w x 16co x 27, co padded to 17 for conflict-free w-broadcast reads).

#define XL_ROWSTRIDE 116
#define XL_SIZE (3*3*7*XL_ROWSTRIDE)
#define WL_WSTRIDE (17*27)
#define WL_SIZE (8*WL_WSTRIDE)

__global__ __launch_bounds__(256, 3)
void patconv3d_fp32(const float* __restrict__ xin,
                    const float* __restrict__ wt,
                    const float* __restrict__ bs,
                    float* __restrict__ out) {
    __shared__ float Xl[XL_SIZE];
    __shared__ float Wl[WL_SIZE];

    const int bid = blockIdx.x;
    const int ct  = bid & 3;          // co tile (0..3) -> co 16*ct..
    const int hb  = (bid >> 2) & 1;   // ho half (0..1)
    const int h   = (bid >> 3) & 7;   // y-pattern
    const int t   = (bid >> 6) & 15;  // time
    const int b   = (bid >> 10) & 1;  // batch

    const int tid = threadIdx.x;
    const int xl  = tid & 127;            // x position (valid < 112)
    const int cg  = tid >> 7;             // 0/1 -> co sub-block of 8
    const int xr  = (xl < 112) ? xl : 111; // clamp for safe LDS reads
    const int wq  = xl & 7;               // x%8 -> w-pattern
    const int cobase = ct * 16 + cg * 8;

    float acc[8][7];
#pragma unroll
    for (int c = 0; c < 8; ++c)
#pragma unroll
        for (int ho = 0; ho < 7; ++ho) acc[c][ho] = 0.f;

    for (int ci = 0; ci < 64; ++ci) {
        __syncthreads();  // previous iteration's reads done before overwrite
        // ---- stage X: rows r=8*ho_abs+h+kh-7, depth d=t+kd-1, cols -7..106
        for (int idx = tid; idx < 3 * 3 * 7 * 114; idx += 256) {
            int c    = idx % 114;
            int rest = idx / 114;
            int ho   = rest % 7;
            rest    /= 7;
            int kh   = rest % 3;
            int kd   = rest / 3;
            int r    = 8 * (hb * 7 + ho) + h + kh - 7;
            int d    = t + kd - 1;
            int col  = c - 7;
            float v = 0.f;
            if (r >= 0 && d >= 0 && d < 16 && col >= 0)
                v = xin[(((b * 64 + ci) * 16 + d) * 112 + r) * 112 + col];
            Xl[((kd * 3 + kh) * 7 + ho) * XL_ROWSTRIDE + c] = v;
        }
        // ---- stage W: [w][co(17 pad)][k27]
        for (int idx = tid; idx < 8 * 16 * 27; idx += 256) {
            int k    = idx % 27;
            int rest = idx / 27;
            int co_l = rest % 16;
            int wi   = rest / 16;
            Wl[wi * WL_WSTRIDE + co_l * 27 + k] =
                wt[(((((h * 8 + wi) * 64) + (ct * 16 + co_l)) * 64 + ci) * 27) + k];
        }
        __syncthreads();
        // ---- compute: 27 k-steps, 56 fma each
#pragma unroll
        for (int kd = 0; kd < 3; ++kd)
#pragma unroll
            for (int kh = 0; kh < 3; ++kh)
#pragma unroll
                for (int kw = 0; kw < 3; ++kw) {
                    const int k = (kd * 3 + kh) * 3 + kw;
                    float xv[7];
#pragma unroll
                    for (int ho = 0; ho < 7; ++ho)
                        xv[ho] = Xl[((kd * 3 + kh) * 7 + ho) * XL_ROWSTRIDE + xr + kw];
                    float wv[8];
#pragma unroll
                    for (int c = 0; c < 8; ++c)
                        wv[c] = Wl[wq * WL_WSTRIDE + (cg * 8 + c) * 27 + k];
#pragma unroll
                    for (int c = 0; c < 8; ++c)
#pragma unroll
                        for (int ho = 0; ho < 7; ++ho)
                            acc[c][ho] += wv[c] * xv[ho];
                }
    }

    // ---- epilogue: add bias, coalesced stores (lanes = consecutive x)
    if (xl < 112) {
#pragma unroll
        for (int c = 0; c < 8; ++c) {
            const int co = cobase + c;
            const float bv = bs[(h * 8 + wq) * 64 + co];
#pragma unroll
            for (int ho = 0; ho < 7; ++ho) {
                const int y = 8 * (hb * 7 + ho) + h;
                out[(((b * 64 + co) * 16 + t) * 112 + y) * 112 + xl] = acc[c][ho] + bv;
            }
        }
    }
}

extern "C" void kernel_launch(void* const* d_in, const int* in_sizes, int n_in,
                              void* d_out, int out_size, void* d_ws, size_t ws_size,
                              hipStream_t stream) {
    const float* x  = (const float*)d_in[0];
    const float* w  = (const float*)d_in[1];
    const float* bi = (const float*)d_in[2];
    float* out = (float*)d_out;
    // grid: ct(4) * hb(2) * h(8) * t(16) * b(2) = 2048 blocks
    patconv3d_fp32<<<dim3(2048), dim3(256), 0, stream>>>(x, w, bi, out);
}

// Round 2
// 470.675 us; speedup vs baseline: 12.0462x; 12.0462x over previous
//
#include <hip/hip_runtime.h>
#include <hip/hip_bf16.h>
#include <stdint.h>

typedef __attribute__((ext_vector_type(8))) short short8;
typedef __attribute__((ext_vector_type(4))) float f32x4;

#define XPP_BYTES 66355200ull   // 8rh*8cw*2b*18d*15*15*64ci*2B
#define WPP_BYTES 14155776ull   // 64hw*27tap*64co*64ci*2B

__device__ __forceinline__ void gl2lds16(const void* g, void* l) {
    __builtin_amdgcn_global_load_lds(
        (const __attribute__((address_space(1))) unsigned int*)g,
        (__attribute__((address_space(3))) unsigned int*)l, 16, 0, 0);
}

// ---------------- T1: X (f32) -> X'' (bf16, space-to-depth, zero-padded) ----
// X''[rh][cw][b][d+1][rho+1][cwo+1][ci]; boundaries pre-zeroed by memset.
__global__ __launch_bounds__(256)
void xform_x(const float* __restrict__ xin, __hip_bfloat16* __restrict__ xpp) {
    __shared__ __hip_bfloat16 lx[8 * 112 * 8];  // [r8][c112][ci8]
    const int bid = blockIdx.x;
    const int rc = bid % 14, d = (bid / 14) % 16, b = bid / 224;
    const int r0 = rc * 8;
    for (int cic = 0; cic < 8; ++cic) {
        __syncthreads();
        for (int f = threadIdx.x; f < 8 * 8 * 112; f += 256) {
            int c = f % 112, r = (f / 112) % 8, ci = f / (112 * 8);
            float v = xin[((((size_t)b * 64 + cic * 8 + ci) * 16 + d) * 112 + (r0 + r)) * 112 + c];
            lx[(r * 112 + c) * 8 + ci] = __float2bfloat16(v);
        }
        __syncthreads();
        for (int f = threadIdx.x; f < 8 * 112; f += 256) {
            int c = f % 112, r = f / 112;
            int rr = r0 + r;
            int rh = rr & 7, rho = rr >> 3, cw = c & 7, cwo = c >> 3;
            size_t dst = ((((((size_t)(rh * 8 + cw) * 2 + b) * 18 + (d + 1)) * 15 + (rho + 1)) * 15) + (cwo + 1)) * 64 + cic * 8;
            uint4 v = *(const uint4*)&lx[(r * 112 + c) * 8];
            *(uint4*)(xpp + dst) = v;
        }
    }
}

// ---------------- T2: W (f32) -> W''[hw][tap][co][ci] (bf16) ---------------
__global__ __launch_bounds__(256)
void xform_w(const float* __restrict__ wt, __hip_bfloat16* __restrict__ wpp) {
    __shared__ __hip_bfloat16 lw[8 * 27 * 72];  // [co8][k27][ci64 pad72]
    const int hw = blockIdx.x;
    for (int cc = 0; cc < 8; ++cc) {
        __syncthreads();
        for (int f = threadIdx.x; f < 8 * 64 * 27; f += 256) {
            int k = f % 27, ci = (f / 27) % 64, co = f / (27 * 64);
            float v = wt[(size_t)hw * 110592 + (size_t)(cc * 8 + co) * 1728 + ci * 27 + k];
            lw[(co * 27 + k) * 72 + ci] = __float2bfloat16(v);
        }
        __syncthreads();
        for (int f = threadIdx.x; f < 27 * 8 * 8; f += 256) {
            int cic = f % 8, co = (f / 8) % 8, k = f / 64;
            uint4 v = *(const uint4*)&lw[(co * 27 + k) * 72 + cic * 8];
            size_t dst = (((size_t)hw * 27 + k) * 64 + (cc * 8 + co)) * 64 + cic * 8;
            *(uint4*)(wpp + dst) = v;
        }
    }
}

// ---------------- GEMM: per (b,t,h,w): [196m x 64co] += A[196 x 64ci] W ----
// grid idx = ((h*8+w)*2+b)*16+t  (w-siblings spaced 32 -> same XCD for L2 write merge)
__global__ __launch_bounds__(256, 2)
void patgemm(const __hip_bfloat16* __restrict__ xpp,
             const __hip_bfloat16* __restrict__ wpp,
             const float* __restrict__ bs,
             float* __restrict__ out) {
    extern __shared__ char smem[];  // A: 2 x 26624 B | B: 2 x 8192 B = 69632
    const int bid = blockIdx.x;
    const int t = bid & 15, b = (bid >> 4) & 1, w = (bid >> 5) & 7, h = (bid >> 8) & 7;
    const int tid = threadIdx.x, wv = tid >> 6, lane = tid & 63;
    const int col = lane & 15, quad = lane >> 4;

    // ---- per-slot staging offsets (tap-independent, statically indexed)
    uint32_t aoff[7];
#pragma unroll
    for (int i = 0; i < 7; ++i) {
        int s = wv + 4 * i; if (s > 24) s = 24;
        int m = s * 8 + (lane >> 3); if (m > 195) m = 195;
        int ho = m / 14, wo = m - ho * 14;
        aoff[i] = (uint32_t)(ho * 1920 + wo * 128 + (((lane & 7) ^ (m & 7)) << 4));
    }
    uint32_t boff[2];
#pragma unroll
    for (int i = 0; i < 2; ++i) {
        int s = wv + 4 * i;
        int co = s * 8 + (lane >> 3);
        boff[i] = (uint32_t)(co * 128 + (((lane & 7) ^ (co & 7)) << 4));
    }

    f32x4 acc[4][4];
#pragma unroll
    for (int mi = 0; mi < 4; ++mi)
#pragma unroll
        for (int n = 0; n < 4; ++n) acc[mi][n] = (f32x4){0.f, 0.f, 0.f, 0.f};

    const char* wbase = (const char*)wpp + ((size_t)(h * 8 + w) * 27) * 8192;

    auto STAGE = [&](int bi, int tap) {
        const int kd = tap / 9, kh = (tap - kd * 9) / 3, kw = tap % 3;
        const int r0 = h + kh - 7, c0 = w + kw - 7;
        const char* ap = (const char*)xpp +
            (size_t)(((((r0 & 7) * 8 + (c0 & 7)) * 2 + b) * 18 + (t + kd)) * 225
                     + ((r0 >> 3) + 1) * 15 + ((c0 >> 3) + 1)) * 128;
        char* Ad = smem + bi * 26624;
#pragma unroll
        for (int i = 0; i < 7; ++i) {
            int s = wv + 4 * i;
            if (s < 25) gl2lds16(ap + aoff[i], Ad + s * 1024);
        }
        const char* bp = wbase + (size_t)tap * 8192;
        char* Bd = smem + 53248 + bi * 8192;
#pragma unroll
        for (int i = 0; i < 2; ++i) {
            int s = wv + 4 * i;
            gl2lds16(bp + boff[i], Bd + s * 1024);
        }
    };

    STAGE(0, 0);
    __syncthreads();

#pragma unroll 1
    for (int tap = 0; tap < 27; ++tap) {
        const int cur = tap & 1;
        if (tap < 26) STAGE(cur ^ 1, tap + 1);
        const char* Ab = smem + cur * 26624;
        const char* Bb = smem + 53248 + cur * 8192;
#pragma unroll
        for (int ks = 0; ks < 2; ++ks) {
            short8 bfr[4];
#pragma unroll
            for (int n = 0; n < 4; ++n) {
                const int co = n * 16 + col;
                bfr[n] = *(const short8*)(Bb + co * 128 + (((ks * 4 + quad) ^ (co & 7)) << 4));
            }
#pragma unroll
            for (int mi = 0; mi < 4; ++mi) {
                const int tile = wv + mi * 4;
                if (tile < 13) {
                    const int m = tile * 16 + col;
                    short8 af = *(const short8*)(Ab + m * 128 + (((ks * 4 + quad) ^ (m & 7)) << 4));
#pragma unroll
                    for (int n = 0; n < 4; ++n)
                        acc[mi][n] = __builtin_amdgcn_mfma_f32_16x16x32_bf16(af, bfr[n], acc[mi][n], 0, 0, 0);
                }
            }
        }
        __syncthreads();
    }

    // ---- epilogue: D layout col=lane&15 (=co), row=quad*4+j (=m)
    const float* bsl = bs + (h * 8 + w) * 64;
#pragma unroll
    for (int mi = 0; mi < 4; ++mi) {
        const int tile = wv + mi * 4;
        if (tile >= 13) continue;
#pragma unroll
        for (int n = 0; n < 4; ++n) {
            const int co = n * 16 + col;
            const float bv = bsl[co];
#pragma unroll
            for (int j = 0; j < 4; ++j) {
                const int m = tile * 16 + quad * 4 + j;
                if (m < 196) {
                    const int ho = m / 14, wo = m - ho * 14;
                    out[(((size_t)(b * 64 + co) * 16 + t) * 112 + 8 * ho + h) * 112 + 8 * wo + w]
                        = acc[mi][n][j] + bv;
                }
            }
        }
    }
}

// ---------------- fallback: round-1 fp32 kernel (used if ws too small) -----
#define XL_ROWSTRIDE 116
#define WL_WSTRIDE (17*27)

__global__ __launch_bounds__(256, 3)
void patconv3d_fp32(const float* __restrict__ xin,
                    const float* __restrict__ wt,
                    const float* __restrict__ bs,
                    float* __restrict__ out) {
    __shared__ float Xl[3*3*7*XL_ROWSTRIDE];
    __shared__ float Wl[8*WL_WSTRIDE];
    const int bid = blockIdx.x;
    const int ct = bid & 3, hb = (bid >> 2) & 1, h = (bid >> 3) & 7;
    const int t = (bid >> 6) & 15, b = (bid >> 10) & 1;
    const int tid = threadIdx.x;
    const int xl = tid & 127, cg = tid >> 7;
    const int xr = (xl < 112) ? xl : 111;
    const int wq = xl & 7;
    float acc[8][7];
#pragma unroll
    for (int c = 0; c < 8; ++c)
#pragma unroll
        for (int ho = 0; ho < 7; ++ho) acc[c][ho] = 0.f;
    for (int ci = 0; ci < 64; ++ci) {
        __syncthreads();
        for (int idx = tid; idx < 3 * 3 * 7 * 114; idx += 256) {
            int c = idx % 114, rest = idx / 114;
            int ho = rest % 7; rest /= 7;
            int kh = rest % 3, kd = rest / 3;
            int r = 8 * (hb * 7 + ho) + h + kh - 7;
            int d = t + kd - 1, colx = c - 7;
            float v = 0.f;
            if (r >= 0 && d >= 0 && d < 16 && colx >= 0)
                v = xin[(((size_t)(b * 64 + ci) * 16 + d) * 112 + r) * 112 + colx];
            Xl[((kd * 3 + kh) * 7 + ho) * XL_ROWSTRIDE + c] = v;
        }
        for (int idx = tid; idx < 8 * 16 * 27; idx += 256) {
            int k = idx % 27, rest = idx / 27;
            int co_l = rest % 16, wi = rest / 16;
            Wl[wi * WL_WSTRIDE + co_l * 27 + k] =
                wt[(((size_t)(h * 8 + wi) * 64 + (ct * 16 + co_l)) * 64 + ci) * 27 + k];
        }
        __syncthreads();
#pragma unroll
        for (int kd = 0; kd < 3; ++kd)
#pragma unroll
            for (int kh = 0; kh < 3; ++kh)
#pragma unroll
                for (int kw = 0; kw < 3; ++kw) {
                    const int k = (kd * 3 + kh) * 3 + kw;
                    float xv[7];
#pragma unroll
                    for (int ho = 0; ho < 7; ++ho)
                        xv[ho] = Xl[((kd * 3 + kh) * 7 + ho) * XL_ROWSTRIDE + xr + kw];
                    float wv[8];
#pragma unroll
                    for (int c = 0; c < 8; ++c)
                        wv[c] = Wl[wq * WL_WSTRIDE + (cg * 8 + c) * 27 + k];
#pragma unroll
                    for (int c = 0; c < 8; ++c)
#pragma unroll
                        for (int ho = 0; ho < 7; ++ho)
                            acc[c][ho] += wv[c] * xv[ho];
                }
    }
    if (xl < 112) {
#pragma unroll
        for (int c = 0; c < 8; ++c) {
            const int co = ct * 16 + cg * 8 + c;
            const float bv = bs[(h * 8 + wq) * 64 + co];
#pragma unroll
            for (int ho = 0; ho < 7; ++ho) {
                const int y = 8 * (hb * 7 + ho) + h;
                out[(((size_t)(b * 64 + co) * 16 + t) * 112 + y) * 112 + xl] = acc[c][ho] + bv;
            }
        }
    }
}

extern "C" void kernel_launch(void* const* d_in, const int* in_sizes, int n_in,
                              void* d_out, int out_size, void* d_ws, size_t ws_size,
                              hipStream_t stream) {
    const float* x  = (const float*)d_in[0];
    const float* wg = (const float*)d_in[1];
    const float* bi = (const float*)d_in[2];
    float* out = (float*)d_out;
    if (ws_size >= XPP_BYTES + WPP_BYTES) {
        __hip_bfloat16* xpp = (__hip_bfloat16*)d_ws;
        __hip_bfloat16* wpp = (__hip_bfloat16*)((char*)d_ws + XPP_BYTES);
        hipMemsetAsync(d_ws, 0, XPP_BYTES, stream);
        xform_x<<<448, 256, 0, stream>>>(x, xpp);
        xform_w<<<64, 256, 0, stream>>>(wg, wpp);
        patgemm<<<2048, 256, 69632, stream>>>(xpp, wpp, bi, out);
    } else {
        patconv3d_fp32<<<2048, 256, 0, stream>>>(x, wg, bi, out);
    }
}

// Round 3
// 281.699 us; speedup vs baseline: 20.1273x; 1.6708x over previous
//
#include <hip/hip_runtime.h>
#include <hip/hip_bf16.h>
#include <stdint.h>

typedef __attribute__((ext_vector_type(8))) short short8;
typedef __attribute__((ext_vector_type(4))) float f32x4;

#define XPP_BYTES 66355200ull   // 8rh*8cw*2b*15rho*15cwo*18d*64ci*2B
#define WPP_BYTES 14155776ull   // 64hw*27tap*64co*64ci*2B

__device__ __forceinline__ void gl2lds16(const void* g, void* l) {
    __builtin_amdgcn_global_load_lds(
        (const __attribute__((address_space(1))) unsigned int*)g,
        (__attribute__((address_space(3))) unsigned int*)l, 16, 0, 0);
}

// ---------------- T1: X (f32) -> X''' (bf16, space-to-depth, d-innermost) --
// X'''[rh][cw][b][rho(15)][cwo(15)][d(18)][ci(64)]; src depth d stored at d+1,
// superpixel row/col stored at +1; planes rho=0, cwo=0, d=0, d=17 pre-zeroed
// by memset. Block = (b, d, rho-group). LDS transpose -> 128B-contig stores.
__global__ __launch_bounds__(512)
void xform_x(const float* __restrict__ xin, __hip_bfloat16* __restrict__ xpp) {
    extern __shared__ __hip_bfloat16 Xl[];  // [r8][c112][ci64] swizzled, 114688 B
    const int bid = blockIdx.x;
    const int rho = bid % 14, d = (bid / 14) % 16, b = bid / 224;
    const int tid = threadIdx.x;
    // phase 1: coalesced float4 loads, scalar bf16 LDS writes (ci-swizzled)
    for (int f = tid; f < 64 * 8 * 28; f += 512) {
        int ci = f / 224, rem = f % 224;
        int r = rem / 28, c4 = (rem % 28) * 4;
        const float4 v = *(const float4*)&xin[
            ((((size_t)b * 64 + ci) * 16 + d) * 112 + (rho * 8 + r)) * 112 + c4];
        const float vv[4] = {v.x, v.y, v.z, v.w};
#pragma unroll
        for (int u = 0; u < 4; ++u) {
            int c = c4 + u;
            Xl[(r * 112 + c) * 64 + (ci ^ ((c & 7) << 3))] = __float2bfloat16(vv[u]);
        }
    }
    __syncthreads();
    // phase 2: 8 lanes emit one position's 128B (ci 0..63 linear at dst)
    for (int f = tid; f < 896 * 8; f += 512) {
        int pos = f >> 3, j = f & 7;
        int r = pos / 112, c = pos % 112;
        int cw = c & 7, cwo = c >> 3;
        uint4 v = *(const uint4*)&Xl[pos * 64 + ((j * 8) ^ ((c & 7) << 3))];
        size_t dst = (((((size_t)(r * 8 + cw) * 2 + b) * 15 + (rho + 1)) * 15
                       + (cwo + 1)) * 18 + (d + 1)) * 64 + j * 8;
        *(uint4*)(xpp + dst) = v;
    }
}

// ---------------- T2: W (f32) -> W''[hw][tap][co][ci] (bf16) ---------------
__global__ __launch_bounds__(256)
void xform_w(const float* __restrict__ wt, __hip_bfloat16* __restrict__ wpp) {
    __shared__ __hip_bfloat16 lw[8 * 27 * 72];  // [co8][k27][ci64 pad72]
    const int hw = blockIdx.x >> 3, cc = blockIdx.x & 7;
    for (int f = threadIdx.x; f < 8 * 64 * 27; f += 256) {
        int k = f % 27, ci = (f / 27) % 64, co = f / (27 * 64);
        float v = wt[(size_t)hw * 110592 + (size_t)(cc * 8 + co) * 1728 + ci * 27 + k];
        lw[(co * 27 + k) * 72 + ci] = __float2bfloat16(v);
    }
    __syncthreads();
    for (int f = threadIdx.x; f < 27 * 8 * 8; f += 256) {
        int cic = f % 8, co = (f / 8) % 8, k = f / 64;
        uint4 v = *(const uint4*)&lw[(co * 27 + k) * 72 + cic * 8];
        size_t dst = (((size_t)hw * 27 + k) * 64 + (cc * 8 + co)) * 64 + cic * 8;
        *(uint4*)(wpp + dst) = v;
    }
}

// ---------------- GEMM: per (h,w,b): [3136m x 64co], m=(ho,wo,t) -----------
// bid: h = bid&7 (XCD), k=bid>>3: w=k&7, b=(k>>3)&1, mc=k>>4 (ho-row 0..13).
// Block: BM=224 (14 wo-tiles x 16t), BK=64 (one tap), 4 waves = 2m x 2n groups.
// A-tile per (wo): 2KB contiguous in X'''. Double-buffered LDS, 1 barrier/tap.
__global__ __launch_bounds__(256, 2)
void patgemm(const __hip_bfloat16* __restrict__ xpp,
             const __hip_bfloat16* __restrict__ wpp,
             const float* __restrict__ bs,
             float* __restrict__ out) {
    extern __shared__ char smem[];  // A: 2 x 28672 | B: 2 x 8192 = 73728
    const int bid = blockIdx.x;
    const int h = bid & 7, k = bid >> 3;
    const int w = k & 7, b = (k >> 3) & 1, mc = k >> 4;
    const int hw = h * 8 + w;
    const int tid = threadIdx.x, wv = tid >> 6, lane = tid & 63;
    const int col = lane & 15, quad = lane >> 4;
    const int mg = wv >> 1, ng = wv & 1;

    // tap-independent per-lane staging offsets
    uint32_t aoff[7], adst[7];
#pragma unroll
    for (int i = 0; i < 7; ++i) {
        int slot = tid + i * 256;           // 0..1791
        int wo = slot >> 7, within = slot & 127;
        int rt = within >> 3, ch = within & 7;
        aoff[i] = (uint32_t)(wo * 2304 + rt * 128 + ((ch ^ (rt & 7)) << 4));
        adst[i] = (uint32_t)(slot * 16);
    }
    uint32_t boff[2], bdst[2];
#pragma unroll
    for (int i = 0; i < 2; ++i) {
        int slot = tid + i * 256;           // 0..511
        int co = slot >> 3, ch = slot & 7;
        boff[i] = (uint32_t)(co * 128 + ((ch ^ (co & 7)) << 4));
        bdst[i] = (uint32_t)(slot * 16);
    }
    // per-lane LDS read offsets (shared by A and B tiles)
    uint32_t lofs[2];
#pragma unroll
    for (int ks = 0; ks < 2; ++ks)
        lofs[ks] = (uint32_t)(col * 128 + (((ks * 4 + quad) ^ (col & 7)) << 4));

    f32x4 acc[7][2];
#pragma unroll
    for (int j = 0; j < 7; ++j)
#pragma unroll
        for (int n = 0; n < 2; ++n) acc[j][n] = (f32x4){0.f, 0.f, 0.f, 0.f};

    const char* wbase = (const char*)wpp + (size_t)hw * 27 * 8192;

    auto STAGE = [&](int bi, int tap) {
        const int kd = tap / 9, kh = (tap / 3) % 3, kw = tap % 3;
        const int r0 = h + kh - 7, c0 = w + kw - 7;
        const int rh = r0 & 7, cw = c0 & 7;
        const int rho = (r0 >> 3) + 1 + mc, cwo = (c0 >> 3) + 1;
        const char* ap = (const char*)xpp +
            (size_t)((((rh * 8 + cw) * 2 + b) * 15 + rho) * 15 + cwo) * 2304
            + kd * 128;
        char* Ad = smem + bi * 28672;
#pragma unroll
        for (int i = 0; i < 7; ++i) gl2lds16(ap + aoff[i], Ad + adst[i]);
        const char* bp = wbase + (size_t)tap * 8192;
        char* Bd = smem + 57344 + bi * 8192;
#pragma unroll
        for (int i = 0; i < 2; ++i) gl2lds16(bp + boff[i], Bd + bdst[i]);
    };

    STAGE(0, 0);
    __syncthreads();

#pragma unroll 1
    for (int tap = 0; tap < 27; ++tap) {
        const int cur = tap & 1;
        if (tap < 26) STAGE(cur ^ 1, tap + 1);
        const char* Ab = smem + cur * 28672;
        const char* Bb = smem + 57344 + cur * 8192;
#pragma unroll
        for (int ks = 0; ks < 2; ++ks) {
            short8 bfr[2];
#pragma unroll
            for (int n = 0; n < 2; ++n)
                bfr[n] = *(const short8*)(Bb + (ng * 2 + n) * 2048 + lofs[ks]);
            short8 af[7];
#pragma unroll
            for (int j = 0; j < 7; ++j)
                af[j] = *(const short8*)(Ab + (mg * 7 + j) * 2048 + lofs[ks]);
            __builtin_amdgcn_s_setprio(1);
#pragma unroll
            for (int j = 0; j < 7; ++j)
#pragma unroll
                for (int n = 0; n < 2; ++n)
                    acc[j][n] = __builtin_amdgcn_mfma_f32_16x16x32_bf16(
                        af[j], bfr[n], acc[j][n], 0, 0, 0);
            __builtin_amdgcn_s_setprio(0);
        }
        __syncthreads();  // drains vmcnt: next buffer staged + reads done
    }

    // epilogue: D col=lane&15 (= co-within-ntile = also t-row source col),
    // row = quad*4+jj (= t). y = 8*mc+h, x = 8*wo+w.
    const float* bsl = bs + hw * 64;
    const int y = 8 * mc + h;
#pragma unroll
    for (int j = 0; j < 7; ++j) {
        const int wo = mg * 7 + j;
        const int x = 8 * wo + w;
#pragma unroll
        for (int n = 0; n < 2; ++n) {
            const int co = (ng * 2 + n) * 16 + col;
            const float bv = bsl[co];
#pragma unroll
            for (int jj = 0; jj < 4; ++jj) {
                const int t = quad * 4 + jj;
                out[((((size_t)b * 64 + co) * 16 + t) * 112 + y) * 112 + x]
                    = acc[j][n][jj] + bv;
            }
        }
    }
}

// ---------------- fallback: round-1 fp32 kernel (used if ws too small) -----
#define XL_ROWSTRIDE 116
#define WL_WSTRIDE (17*27)

__global__ __launch_bounds__(256, 3)
void patconv3d_fp32(const float* __restrict__ xin,
                    const float* __restrict__ wt,
                    const float* __restrict__ bs,
                    float* __restrict__ out) {
    __shared__ float Xl[3*3*7*XL_ROWSTRIDE];
    __shared__ float Wl[8*WL_WSTRIDE];
    const int bid = blockIdx.x;
    const int ct = bid & 3, hb = (bid >> 2) & 1, h = (bid >> 3) & 7;
    const int t = (bid >> 6) & 15, b = (bid >> 10) & 1;
    const int tid = threadIdx.x;
    const int xl = tid & 127, cg = tid >> 7;
    const int xr = (xl < 112) ? xl : 111;
    const int wq = xl & 7;
    float acc[8][7];
#pragma unroll
    for (int c = 0; c < 8; ++c)
#pragma unroll
        for (int ho = 0; ho < 7; ++ho) acc[c][ho] = 0.f;
    for (int ci = 0; ci < 64; ++ci) {
        __syncthreads();
        for (int idx = tid; idx < 3 * 3 * 7 * 114; idx += 256) {
            int c = idx % 114, rest = idx / 114;
            int ho = rest % 7; rest /= 7;
            int kh = rest % 3, kd = rest / 3;
            int r = 8 * (hb * 7 + ho) + h + kh - 7;
            int d = t + kd - 1, colx = c - 7;
            float v = 0.f;
            if (r >= 0 && d >= 0 && d < 16 && colx >= 0)
                v = xin[(((size_t)(b * 64 + ci) * 16 + d) * 112 + r) * 112 + colx];
            Xl[((kd * 3 + kh) * 7 + ho) * XL_ROWSTRIDE + c] = v;
        }
        for (int idx = tid; idx < 8 * 16 * 27; idx += 256) {
            int k = idx % 27, rest = idx / 27;
            int co_l = rest % 16, wi = rest / 16;
            Wl[wi * WL_WSTRIDE + co_l * 27 + k] =
                wt[(((size_t)(h * 8 + wi) * 64 + (ct * 16 + co_l)) * 64 + ci) * 27 + k];
        }
        __syncthreads();
#pragma unroll
        for (int kd = 0; kd < 3; ++kd)
#pragma unroll
            for (int kh = 0; kh < 3; ++kh)
#pragma unroll
                for (int kw = 0; kw < 3; ++kw) {
                    const int k = (kd * 3 + kh) * 3 + kw;
                    float xv[7];
#pragma unroll
                    for (int ho = 0; ho < 7; ++ho)
                        xv[ho] = Xl[((kd * 3 + kh) * 7 + ho) * XL_ROWSTRIDE + xr + kw];
                    float wv[8];
#pragma unroll
                    for (int c = 0; c < 8; ++c)
                        wv[c] = Wl[wq * WL_WSTRIDE + (cg * 8 + c) * 27 + k];
#pragma unroll
                    for (int c = 0; c < 8; ++c)
#pragma unroll
                        for (int ho = 0; ho < 7; ++ho)
                            acc[c][ho] += wv[c] * xv[ho];
                }
    }
    if (xl < 112) {
#pragma unroll
        for (int c = 0; c < 8; ++c) {
            const int co = ct * 16 + cg * 8 + c;
            const float bv = bs[(h * 8 + wq) * 64 + co];
#pragma unroll
            for (int ho = 0; ho < 7; ++ho) {
                const int y = 8 * (hb * 7 + ho) + h;
                out[(((size_t)(b * 64 + co) * 16 + t) * 112 + y) * 112 + xl] = acc[c][ho] + bv;
            }
        }
    }
}

extern "C" void kernel_launch(void* const* d_in, const int* in_sizes, int n_in,
                              void* d_out, int out_size, void* d_ws, size_t ws_size,
                              hipStream_t stream) {
    const float* x  = (const float*)d_in[0];
    const float* wg = (const float*)d_in[1];
    const float* bi = (const float*)d_in[2];
    float* out = (float*)d_out;
    if (ws_size >= XPP_BYTES + WPP_BYTES) {
        __hip_bfloat16* xpp = (__hip_bfloat16*)d_ws;
        __hip_bfloat16* wpp = (__hip_bfloat16*)((char*)d_ws + XPP_BYTES);
        hipMemsetAsync(d_ws, 0, XPP_BYTES, stream);
        xform_x<<<448, 512, 114688, stream>>>(x, xpp);
        xform_w<<<512, 256, 0, stream>>>(wg, wpp);
        patgemm<<<1792, 256, 73728, stream>>>(xpp, wpp, bi, out);
    } else {
        patconv3d_fp32<<<2048, 256, 0, stream>>>(x, wg, bi, out);
    }
}